// Round 7
// baseline (991.800 us; speedup 1.0000x reference)
//
#include <hip/hip_runtime.h>
#include <math.h>

// Entmax alpha=1.5 quirk-faithful port. z: [2048, 32000] fp32.
//
// R9 = R7 skeleton + forced 8-deep load batching WITH the registers to hold it.
// Ladder evidence: R7 (VGPR=20) = 1 outstanding load/wave -> 2.4 TB/s;
// R8 (launch_bounds cap 64) spilled its 8-float4 batch to scratch (VGPR=32,
// WRITE inflated 259->362 MB) -> 3.0 TB/s. Every round the occupancy request
// starved the register allocator and killed memory-level parallelism.
// R9: __launch_bounds__(256,6) -> VGPR cap ~84 (6 blocks/CU, 24 waves).
// Streaming loop = 4 batches of {8 back-to-back float4 loads | sched_barrier |
// 8 zero-stores | sched_barrier | 32x branchless top-4 insert | sched_barrier}.
// Single-BB straight-line code: the pins hold (R6's sink was cross-block), and
// pinned order forces the 8 loads' destinations live across the wait -> 8KB
// in flight per wave, ~190KB per CU.
//
// Everything else is R7's proven absmax==0.0 code, verbatim:
//  - top-4 (value,index) cache; cutoff = rowmax-1.0625; if v3 <= cutoff all
//    candidates are cached and the largest non-candidate is a cache slot;
//    else (P~4e-5/thread) exact per-thread re-read fallback (500 B, L2-hot).
//  - zero-fill during pass 1 (fire-and-forget) + post-tau scattered fix-up;
//    B3 (__syncthreads, vmcnt-draining) orders fix-up after zero-stores.
//  - tau: candidates={z>cutoff}, rank-sort (ties by slot), sequential fp32
//    cumsum, mask=s-(cs-1)/t>0, k=popcount, cs_k=prefix[k-1]+sorted[k]
//    (mx2 = largest non-candidate when k==m), tau=(cs_k-1)/k.
// Tail (8192>8000): clamped load address + -INF value mask keeps batches
// uniform (-INF never beats v3, never a candidate, no-op in fmax folds);
// zero-stores exec-mask guarded.

constexpr int NCOL     = 32000;
constexpr int NF4      = NCOL / 4;   // 8000 float4 per row
constexpr int TPB      = 256;
constexpr int NBATCH   = 4;          // 4 batches x 8 float4 x 256 thr = 8192
constexpr int BDEPTH   = 8;
constexpr int NWAVE    = TPB / 64;   // 4
constexpr int CAND_CAP = 1024;       // data gives ~46 candidates/row
constexpr int SORT_CAP = 80;         // need sorted[0..64]

// LDS-only barrier: no vmcnt drain -> load/zero-store streams stay in flight.
#define BAR_LDS() do {                                     \
    asm volatile("s_waitcnt lgkmcnt(0)" ::: "memory");     \
    __builtin_amdgcn_sched_barrier(0);                     \
    __builtin_amdgcn_s_barrier();                          \
    __builtin_amdgcn_sched_barrier(0);                     \
  } while (0)

#define APPEND(xx, gi)                                                   \
  { int _s = atomicAdd(&s_cnt, 1);                                       \
    if (_s < CAND_CAP) { s_cand_v[_s] = (xx); s_cand_i[_s] = (gi); } }

// Branchless sorted insert of (xx,gi) into (v0>=v1>=v2>=v3) with indices.
__device__ __forceinline__ void ins4(float& v0, float& v1, float& v2, float& v3,
                                     int& i0, int& i1, int& i2, int& i3,
                                     float xx, int gi) {
  float t = xx; int ti = gi;
  { const bool b = t > v0; const float dv = b ? v0 : t; const int di = b ? i0 : ti;
    v0 = b ? t : v0; i0 = b ? ti : i0; t = dv; ti = di; }
  { const bool b = t > v1; const float dv = b ? v1 : t; const int di = b ? i1 : ti;
    v1 = b ? t : v1; i1 = b ? ti : i1; t = dv; ti = di; }
  { const bool b = t > v2; const float dv = b ? v2 : t; const int di = b ? i2 : ti;
    v2 = b ? t : v2; i2 = b ? ti : i2; t = dv; ti = di; }
  { const bool b = t > v3;
    v3 = b ? t : v3; i3 = b ? ti : i3; }
}

__global__ __launch_bounds__(TPB, 6) void entmax15_kernel(const float* __restrict__ z,
                                                          float* __restrict__ out) {
  const int row  = blockIdx.x;
  const int tid  = threadIdx.x;
  const int wave = tid >> 6;

  __shared__ float s_cand_v[CAND_CAP];
  __shared__ int   s_cand_i[CAND_CAP];
  __shared__ float s_sorted[SORT_CAP];
  __shared__ float s_red[NWAVE];
  __shared__ float s_red2[NWAVE];
  __shared__ int   s_cnt;
  __shared__ float s_tau;

  if (tid == 0) s_cnt = 0;
  if (tid < SORT_CAP) s_sorted[tid] = -INFINITY;

  const float4* zrow = reinterpret_cast<const float4*>(z) + (size_t)row * NF4;
  float4* orow = reinterpret_cast<float4*>(out) + (size_t)row * NF4;
  const float4 zero4 = make_float4(0.0f, 0.0f, 0.0f, 0.0f);

  // ---- Pass 1: 4 batches of 8-deep loads + zero-stores + top-4 ----
  float v0 = -INFINITY, v1 = -INFINITY, v2 = -INFINITY, v3 = -INFINITY;
  int   i0 = 0, i1 = 0, i2 = 0, i3 = 0;
#pragma unroll
  for (int b = 0; b < NBATCH; ++b) {
    float4 r[BDEPTH];  // constant-indexed after unroll -> registers
#pragma unroll
    for (int j = 0; j < BDEPTH; ++j) {
      const int idx = (b * BDEPTH + j) * TPB + tid;
      r[j] = zrow[(idx < NF4) ? idx : 0];      // clamped: batch stays uniform
    }
    __builtin_amdgcn_sched_barrier(0);         // all 8 loads issued first
#pragma unroll
    for (int j = 0; j < BDEPTH; ++j) {
      const int idx = (b * BDEPTH + j) * TPB + tid;
      if (idx < NF4) orow[idx] = zero4;        // exec-masked, fire-and-forget
    }
    __builtin_amdgcn_sched_barrier(0);         // stores issued before VALU chain
#pragma unroll
    for (int j = 0; j < BDEPTH; ++j) {
      const int idx  = (b * BDEPTH + j) * TPB + tid;
      const bool ok  = idx < NF4;
      const int base = idx * 4;
      const float a0 = ok ? r[j].x : -INFINITY;
      const float a1 = ok ? r[j].y : -INFINITY;
      const float a2 = ok ? r[j].z : -INFINITY;
      const float a3 = ok ? r[j].w : -INFINITY;
      ins4(v0, v1, v2, v3, i0, i1, i2, i3, a0, base + 0);
      ins4(v0, v1, v2, v3, i0, i1, i2, i3, a1, base + 1);
      ins4(v0, v1, v2, v3, i0, i1, i2, i3, a2, base + 2);
      ins4(v0, v1, v2, v3, i0, i1, i2, i3, a3, base + 3);
    }
    __builtin_amdgcn_sched_barrier(0);         // batch boundary: no cross-hoist
  }

  // Thread max is v0 (every thread owns >= 124 real elements).
  float lmax = v0;
#pragma unroll
  for (int off = 32; off > 0; off >>= 1)
    lmax = fmaxf(lmax, __shfl_down(lmax, off));
  if ((tid & 63) == 0) s_red[wave] = lmax;
  BAR_LDS();  // B1: row max ready; s_cnt init visible

  const float gmax   = fmaxf(fmaxf(s_red[0], s_red[1]), fmaxf(s_red[2], s_red[3]));
  const float cutoff = gmax - 1.0625f;

  // ---- Phase 2 (no memory in common case): emit candidates, max of the rest ----
  float lmax2 = -INFINITY;
  if (v3 > cutoff) {
    // Rare exact fallback: this thread may hold >4 candidates; re-read its 500 B.
    for (int it = 0; it < NBATCH * BDEPTH; ++it) {
      const int idx = it * TPB + tid;
      if (idx < NF4) {
        const float4 x = zrow[idx];
        const int base = idx * 4;
        if (x.x > cutoff) { APPEND(x.x, base + 0) } else lmax2 = fmaxf(lmax2, x.x);
        if (x.y > cutoff) { APPEND(x.y, base + 1) } else lmax2 = fmaxf(lmax2, x.y);
        if (x.z > cutoff) { APPEND(x.z, base + 2) } else lmax2 = fmaxf(lmax2, x.z);
        if (x.w > cutoff) { APPEND(x.w, base + 3) } else lmax2 = fmaxf(lmax2, x.w);
      }
    }
  } else {
    if (v0 > cutoff) { APPEND(v0, i0) } else lmax2 = fmaxf(lmax2, v0);
    if (v1 > cutoff) { APPEND(v1, i1) } else lmax2 = fmaxf(lmax2, v1);
    if (v2 > cutoff) { APPEND(v2, i2) } else lmax2 = fmaxf(lmax2, v2);
    if (v3 > cutoff) { APPEND(v3, i3) } else lmax2 = fmaxf(lmax2, v3);
    // All uncached values <= v3 <= cutoff: non-candidates, dominated by the
    // largest cached <=cutoff slot, captured exactly above.
  }
#pragma unroll
  for (int off = 32; off > 0; off >>= 1)
    lmax2 = fmaxf(lmax2, __shfl_down(lmax2, off));
  if ((tid & 63) == 0) s_red2[wave] = lmax2;
  BAR_LDS();  // B2: candidate set + max-of-rest ready

  // ---- Phase 3+4 (wave 0 only, fused): rank-sort + exact sequential tau ----
  if (tid < 64) {
    const int m = min(s_cnt, CAND_CAP);
    for (int c = tid; c < m; c += 64) {
      const float val = s_cand_v[c];
      int rank = 0;
      for (int i = 0; i < m; ++i) {
        const float cv = s_cand_v[i];
        rank += (cv > val) || (cv == val && i < c);
      }
      if (rank < SORT_CAP) s_sorted[rank] = val;
    }
    float mx2 = fmaxf(fmaxf(s_red2[0], s_red2[1]), fmaxf(s_red2[2], s_red2[3]));
    const int me = (m < 64) ? m : 64;
    const float sv = (tid < me) ? s_sorted[tid] : 0.0f;
    float cs = 0.0f, prefix = 0.0f;
    for (int j = 0; j < me; ++j) {          // bitwise-identical sequential cumsum
      const float vj = __shfl(sv, j);
      cs += vj;
      if (j == tid) prefix = cs;
    }
    bool maskb = false;
    if (tid < me) {
      const float t = (float)(tid + 1);
      const float q = (prefix - 1.0f) / t;
      maskb = (sv - q) > 0.0f;
    }
    const unsigned long long bal = __ballot(maskb);
    const int k = __popcll(bal);            // k >= 1 (row max is a candidate)
    const float pkm1 = __shfl(prefix, k - 1);
    const float snext = (k < m) ? s_sorted[k] : mx2;  // sorted_z[k]
    const float cs_k = pkm1 + snext;        // numpy cs[k], same add order
    if (tid == 0) s_tau = (cs_k - 1.0f) / (float)k;
  }
  __syncthreads();  // B3: tau ready; vmcnt drained -> zero-stores before fix-up

  // ---- Phase 5: scattered fix-up of the ~m candidate positions ----
  const float tau = s_tau;
  const int m = min(s_cnt, CAND_CAP);
  for (int c = tid; c < m; c += TPB) {
    const float r0 = fmaxf(s_cand_v[c] - tau, 0.0f);
    out[(size_t)row * NCOL + s_cand_i[c]] = r0 * sqrtf(r0);
  }
}

extern "C" void kernel_launch(void* const* d_in, const int* in_sizes, int n_in,
                              void* d_out, int out_size, void* d_ws, size_t ws_size,
                              hipStream_t stream) {
  const float* z = (const float*)d_in[0];
  float* out = (float*)d_out;
  const int rows = in_sizes[0] / NCOL;  // 2048
  hipLaunchKernelGGL(entmax15_kernel, dim3(rows), dim3(TPB), 0, stream, z, out);
}

// Round 8
// 451.596 us; speedup vs baseline: 2.1962x; 2.1962x over previous
//
#include <hip/hip_runtime.h>
#include <math.h>

// Entmax alpha=1.5 quirk-faithful port. z: [2048, 32000] fp32.
//
// R10: full-row register residency with INLINE-ASM load batching. Rounds R6-R9
// proved hipcc's register allocator deletes any source-level MLP scheme
// (R7: VGPR=20 -> 1 load in flight, 2.4 TB/s; R8/R9: spilled the batch to
// scratch, WRITE 259->362/1453 MB). Fills stream 6.4 TB/s at 10% occupancy --
// the requirement is outstanding-queue depth, not waves. So R10 issues all 32
// float4 loads per thread as `asm volatile global_load_dwordx4` (volatile =
// cannot be sunk, split, or reordered by the compiler), then consumes in 4
// groups behind counted `s_waitcnt vmcnt(24/16/8/0)` + sched_barrier(0)
// (rule #18). 32 KB in flight per wave, ~256-384 KB per CU.
//
// __launch_bounds__(256,2): VGPR cap 256 -> 128 data regs fit WITHOUT spill.
// Low occupancy (2-3 blocks/CU) is intentional; fill-kernel evidence says BW
// does not need occupancy, only queue depth.
//
// No zero-fill, no fix-up, no top-4: after tau, one branchless write pass
// computes the reference formula for every element (r0 = fmax(z-tau,0);
// out = r0*sqrt(r0); exact 0 for non-candidates since z <= cutoff < tau).
// Exactly-once stores -> all barriers LDS-only; no stores during the load
// phase -> vmcnt counting is pure (our 32 loads are the only vmem ops).
//
// tau path byte-for-byte the proven absmax==0.0 code: candidates =
// {z > rowmax-1.0625} (appended from registers; tail lanes masked with -INF
// sentinels), rank-sort (ties by slot), sequential fp32 cumsum, mask =
// s-(cs-1)/t > 0, k = popcount, cs_k = prefix[k-1] + sorted[k] (mx2 = largest
// non-candidate when k==m), tau = (cs_k-1)/k.

constexpr int NCOL     = 32000;
constexpr int NF4      = NCOL / 4;   // 8000 float4 per row
constexpr int TPB      = 256;
constexpr int PER_TH   = 32;         // 32*256 = 8192 >= 8000 (tail: it==31, tid>=64)
constexpr int NWAVE    = TPB / 64;   // 4
constexpr int CAND_CAP = 1024;       // data gives ~46 candidates/row
constexpr int SORT_CAP = 80;         // need sorted[0..64]

// LDS-only barrier: no vmcnt drain -> load/store streams stay in flight.
#define BAR_LDS() do {                                     \
    asm volatile("s_waitcnt lgkmcnt(0)" ::: "memory");     \
    __builtin_amdgcn_sched_barrier(0);                     \
    __builtin_amdgcn_s_barrier();                          \
    __builtin_amdgcn_sched_barrier(0);                     \
  } while (0)

// Counted vmem wait + scheduling fence (rule #18: consumption must not be
// hoisted above the wait -- the compiler doesn't know the asm is a load).
#define WAITV(n) do {                                          \
    asm volatile("s_waitcnt vmcnt(" #n ")" ::: "memory");      \
    __builtin_amdgcn_sched_barrier(0);                         \
  } while (0)

#define APPEND(xx)                                                       \
  { int _s = atomicAdd(&s_cnt, 1);                                       \
    if (_s < CAND_CAP) s_cand_v[_s] = (xx); }

typedef float v4f __attribute__((ext_vector_type(4)));

__global__ __launch_bounds__(TPB, 2) void entmax15_kernel(const float* __restrict__ z,
                                                          float* __restrict__ out) {
  const int row  = blockIdx.x;
  const int tid  = threadIdx.x;
  const int wave = tid >> 6;

  __shared__ float s_cand_v[CAND_CAP];
  __shared__ float s_sorted[SORT_CAP];
  __shared__ float s_red[NWAVE];
  __shared__ float s_red2[NWAVE];
  __shared__ int   s_cnt;
  __shared__ float s_tau;

  if (tid == 0) s_cnt = 0;
  if (tid < SORT_CAP) s_sorted[tid] = -INFINITY;

  const float4* zrow = reinterpret_cast<const float4*>(z) + (size_t)row * NF4;
  float4* orow = reinterpret_cast<float4*>(out) + (size_t)row * NF4;

  // ---- Load phase: 32 back-to-back asm loads (volatile: pinned, 32-deep) ----
  v4f r[PER_TH];
#pragma unroll
  for (int it = 0; it < PER_TH; ++it) {
    const int idx = it * TPB + tid;
    const float4* p = zrow + ((idx < NF4) ? idx : 0);  // clamped tail (in-row)
    asm volatile("global_load_dwordx4 %0, %1, off"
                 : "=v"(r[it]) : "v"(p) : "memory");
  }

  // ---- Max phase: consume in 4 groups of 8 behind counted waits ----
  float pm = -INFINITY;
  WAITV(24);
#pragma unroll
  for (int it = 0; it < 8; ++it)
    pm = fmaxf(pm, fmaxf(fmaxf(r[it].x, r[it].y), fmaxf(r[it].z, r[it].w)));
  WAITV(16);
#pragma unroll
  for (int it = 8; it < 16; ++it)
    pm = fmaxf(pm, fmaxf(fmaxf(r[it].x, r[it].y), fmaxf(r[it].z, r[it].w)));
  WAITV(8);
#pragma unroll
  for (int it = 16; it < 24; ++it)
    pm = fmaxf(pm, fmaxf(fmaxf(r[it].x, r[it].y), fmaxf(r[it].z, r[it].w)));
  WAITV(0);
#pragma unroll
  for (int it = 24; it < PER_TH; ++it) {
    const bool ok = (it * TPB + tid) < NF4;  // only it==31 can fail
    const float m4 = fmaxf(fmaxf(r[it].x, r[it].y), fmaxf(r[it].z, r[it].w));
    pm = fmaxf(pm, ok ? m4 : -INFINITY);
  }

  float lmax = pm;
#pragma unroll
  for (int off = 32; off > 0; off >>= 1)
    lmax = fmaxf(lmax, __shfl_down(lmax, off));
  if ((tid & 63) == 0) s_red[wave] = lmax;
  BAR_LDS();  // B1: row max ready; s_cnt init visible

  const float gmax   = fmaxf(fmaxf(s_red[0], s_red[1]), fmaxf(s_red[2], s_red[3]));
  const float cutoff = gmax - 1.0625f;

  // ---- Candidate scan from registers; max of the rest (tail masked -INF) ----
  float lmax2 = -INFINITY;
#pragma unroll
  for (int it = 0; it < PER_TH; ++it) {
    const bool ok = (it * TPB + tid) < NF4;
    const float c0 = ok ? r[it].x : -INFINITY;
    const float c1 = ok ? r[it].y : -INFINITY;
    const float c2 = ok ? r[it].z : -INFINITY;
    const float c3 = ok ? r[it].w : -INFINITY;
    if (c0 > cutoff) { APPEND(c0) } else lmax2 = fmaxf(lmax2, c0);
    if (c1 > cutoff) { APPEND(c1) } else lmax2 = fmaxf(lmax2, c1);
    if (c2 > cutoff) { APPEND(c2) } else lmax2 = fmaxf(lmax2, c2);
    if (c3 > cutoff) { APPEND(c3) } else lmax2 = fmaxf(lmax2, c3);
  }
#pragma unroll
  for (int off = 32; off > 0; off >>= 1)
    lmax2 = fmaxf(lmax2, __shfl_down(lmax2, off));
  if ((tid & 63) == 0) s_red2[wave] = lmax2;
  BAR_LDS();  // B2: candidate set + max-of-rest ready

  // ---- wave 0 (fused): rank-sort + exact sequential tau ----
  if (tid < 64) {
    const int m = min(s_cnt, CAND_CAP);
    for (int c = tid; c < m; c += 64) {
      const float val = s_cand_v[c];
      int rank = 0;
      for (int i = 0; i < m; ++i) {
        const float cv = s_cand_v[i];
        rank += (cv > val) || (cv == val && i < c);
      }
      if (rank < SORT_CAP) s_sorted[rank] = val;
    }
    float mx2 = fmaxf(fmaxf(s_red2[0], s_red2[1]), fmaxf(s_red2[2], s_red2[3]));
    const int me = (m < 64) ? m : 64;
    const float sv = (tid < me) ? s_sorted[tid] : 0.0f;
    float cs = 0.0f, prefix = 0.0f;
    for (int j = 0; j < me; ++j) {          // bitwise-identical sequential cumsum
      const float vj = __shfl(sv, j);
      cs += vj;
      if (j == tid) prefix = cs;
    }
    bool maskb = false;
    if (tid < me) {
      const float t = (float)(tid + 1);
      const float q = (prefix - 1.0f) / t;
      maskb = (sv - q) > 0.0f;
    }
    const unsigned long long bal = __ballot(maskb);
    const int k = __popcll(bal);            // k >= 1 (row max is a candidate)
    const float pkm1 = __shfl(prefix, k - 1);
    const float snext = (k < m) ? s_sorted[k] : mx2;  // sorted_z[k]
    const float cs_k = pkm1 + snext;        // numpy cs[k], same add order
    if (tid == 0) s_tau = (cs_k - 1.0f) / (float)k;
  }
  BAR_LDS();  // B3: tau ready (LDS-only; exactly-once stores need no ordering)

  // ---- Write phase: single branchless pass, reference formula everywhere ----
  const float tau = s_tau;
#pragma unroll
  for (int it = 0; it < PER_TH; ++it) {
    const int idx = it * TPB + tid;
    if (idx < NF4) {
      float4 o;
      const float t0 = fmaxf(r[it].x - tau, 0.0f); o.x = t0 * sqrtf(t0);
      const float t1 = fmaxf(r[it].y - tau, 0.0f); o.y = t1 * sqrtf(t1);
      const float t2 = fmaxf(r[it].z - tau, 0.0f); o.z = t2 * sqrtf(t2);
      const float t3 = fmaxf(r[it].w - tau, 0.0f); o.w = t3 * sqrtf(t3);
      orow[idx] = o;
    }
  }
}

extern "C" void kernel_launch(void* const* d_in, const int* in_sizes, int n_in,
                              void* d_out, int out_size, void* d_ws, size_t ws_size,
                              hipStream_t stream) {
  const float* z = (const float*)d_in[0];
  float* out = (float*)d_out;
  const int rows = in_sizes[0] / NCOL;  // 2048
  hipLaunchKernelGGL(entmax15_kernel, dim3(rows), dim3(TPB), 0, stream, z, out);
}